// Round 14
// baseline (205.569 us; speedup 1.0000x reference)
//
#include <hip/hip_runtime.h>
#include <math.h>

#define NN      512     // N (columns of x)
#define KK      513     // K
#define BB      65536   // batch
#define TROWS   512     // table rows, t = 0..511
#define TCOLS   513     // table cols, g = 0..512
#define T16STR  528     // u32 stride per table row (2112 B, 64B-aligned)

#define TILE_R  32            // rows per tile
#define TPB     4             // tiles per block (software pipeline, 2 LDS buffers)
#define BLK     256           // 4 waves; thread = (row r=tid&31, seg s=tid>>5)
#define XSTR    129           // LDS words per row (128 chunks + 1 pad)
#define TILE_I4 (TILE_R * NN / 4)   // int4 per tile = 4096

typedef int iv4 __attribute__((ext_vector_type(4)));

__device__ __forceinline__ unsigned f2bf(float f) {   // RNE f32 -> bf16 (finite only)
    unsigned u = __float_as_uint(f);
    return (u + 0x7fffu + ((u >> 16) & 1u)) >> 16;
}

// T16[t*T16STR + g] = pack(bf16 logsm(c=0), bf16 logsm(c=1)); edges/unreachable = 0.
// Block 0 wave 0 additionally builds logE[k] = endW[k] - lse(endW).
__global__ void build_table_kernel(const float* __restrict__ W, const float* __restrict__ endW,
                                   unsigned* __restrict__ T16, float* __restrict__ logE) {
    int idx = blockIdx.x * blockDim.x + threadIdx.x;
    if (idx < TROWS * TCOLS) {
        int t = idx / TCOLS;
        int g = idx - t * TCOLS;
        float v0 = 0.f, v1 = 0.f;
        if (t >= 1 && g >= 1 && g <= t) {
            const float* w = W + ((size_t)(t - 1) * (KK - 1) + (g - 1)) * 2;
            float w0 = w[0], w1 = w[1];
            float m  = fmaxf(w0, w1);
            float lse = m + __logf(__expf(w0 - m) + __expf(w1 - m));
            v0 = w0 - lse;
            v1 = w1 - lse;
        }
        T16[t * T16STR + g] = f2bf(v0) | (f2bf(v1) << 16);
    }
    if (blockIdx.x == 0 && threadIdx.x < 64) {
        int lane = threadIdx.x;
        float vals[9];
        float m = -1e30f;
        #pragma unroll
        for (int k = 0; k < 9; ++k) {
            int i = lane + 64 * k;
            vals[k] = (i < KK) ? endW[i] : -1e30f;
            m = fmaxf(m, vals[k]);
        }
        #pragma unroll
        for (int d = 32; d >= 1; d >>= 1) m = fmaxf(m, __shfl_xor(m, d, 64));
        float s = 0.f;
        #pragma unroll
        for (int k = 0; k < 9; ++k) s += __expf(vals[k] - m);
        #pragma unroll
        for (int d = 32; d >= 1; d >>= 1) s += __shfl_xor(s, d, 64);
        float lse = m + __logf(s);
        #pragma unroll
        for (int k = 0; k < 9; ++k) {
            int i = lane + 64 * k;
            if (i < KK) logE[i] = endW[i] - lse;
        }
    }
}

// 256 threads = 32 rows x 8 segs(64 cols); 4-tile software pipeline on 2 LDS
// buffers. Per tile: read own-seg words, popc+prefix -> g, issue ALL 64
// gathers, consume 48, issue next tile's 16 staged loads (younger than every
// gather -> no consume drains them), consume last 16, pack+ds_write staged,
// barrier, reduce. Staged loads stream on HBM during the gather phase.
__global__ __launch_bounds__(BLK, 4) void pc_main_kernel(
    const int* __restrict__ x, const unsigned* __restrict__ T16,
    const float* __restrict__ logE, float* __restrict__ out)
{
    __shared__ unsigned xb[2][TILE_R * XSTR];   // byte-packed: word = 4 cols of one row
    __shared__ int      segsum[8 * TILE_R];
    __shared__ float    partial[8 * TILE_R];

    const int tid  = threadIdx.x;
    const int r    = tid & 31;          // row within tile
    const int s    = tid >> 5;          // 64-col segment (0..7)
    const int row0 = blockIdx.x * (TILE_R * TPB);

    const iv4* tb = (const iv4*)(x + (size_t)row0 * NN);   // TILE_I4=4096 int4 per tile

    // ---- prologue: load tile 0, pack, stage to LDS buf 0 ----
    iv4 A[16];
    #pragma unroll
    for (int j = 0; j < 16; ++j) A[j] = __builtin_nontemporal_load(&tb[tid + BLK * j]);
    #pragma unroll
    for (int j = 0; j < 16; ++j) {
        int i = tid + BLK * j;
        unsigned m = (unsigned)(A[j].x & 1) | ((unsigned)(A[j].y & 1) << 8)
                   | ((unsigned)(A[j].z & 1) << 16) | ((unsigned)(A[j].w & 1) << 24);
        xb[0][(i >> 7) * XSTR + (i & 127)] = m;
    }
    __syncthreads();

    #pragma unroll
    for (int t = 0; t < TPB; ++t) {
        const int cur = t & 1;
        // ---- own-segment words + popcount ----
        unsigned w[16];
        int ssum = 0;
        #pragma unroll
        for (int m = 0; m < 16; ++m) {
            w[m] = xb[cur][r * XSTR + s * 16 + m];  // (r*129+16s+m)%32 spans banks: free
            ssum += __popc(w[m]);                   // bytes are 0x00/0x01
        }
        segsum[s * TILE_R + r] = ssum;
        __syncthreads();

        int g = 0, gtot = 0;
        #pragma unroll
        for (int q = 0; q < 8; ++q) {
            int v = segsum[q * TILE_R + r];
            if (q < s) g += v;
            gtot += v;
        }

        // ---- issue ALL 64 gathers (one table row pair per wave-instr) ----
        unsigned u[64];
        const unsigned* Ts = T16 + (size_t)(s * 64) * T16STR;
        #pragma unroll
        for (int m = 0; m < 16; ++m) {
            #pragma unroll
            for (int q = 0; q < 4; ++q) {
                int b = (w[m] >> (8 * q)) & 1;
                g += b;
                u[4 * m + q] = Ts[(4 * m + q) * T16STR + g];
            }
        }

        // ---- consume gathers 0..47 ----
        float a0 = 0.f, a1 = 0.f, a2 = 0.f, a3 = 0.f;
        #pragma unroll
        for (int k = 0; k < 48; ++k) {
            int b = (w[k >> 2] >> (8 * (k & 3))) & 1;
            float v = __uint_as_float(b ? (u[k] & 0xffff0000u) : (u[k] << 16));
            if      ((k & 3) == 0) a0 += v;
            else if ((k & 3) == 1) a1 += v;
            else if ((k & 3) == 2) a2 += v;
            else                   a3 += v;
        }

        // ---- issue next tile's staged loads (younger than all gathers) ----
        if (t + 1 < TPB) {
            __builtin_amdgcn_sched_barrier(0);
            #pragma unroll
            for (int j = 0; j < 16; ++j)
                A[j] = __builtin_nontemporal_load(&tb[(t + 1) * TILE_I4 + tid + BLK * j]);
            __builtin_amdgcn_sched_barrier(0);
        }

        // ---- consume gathers 48..63 (older than staged: no drain) ----
        #pragma unroll
        for (int k = 48; k < 64; ++k) {
            int b = (w[k >> 2] >> (8 * (k & 3))) & 1;
            float v = __uint_as_float(b ? (u[k] & 0xffff0000u) : (u[k] << 16));
            if      ((k & 3) == 0) a0 += v;
            else if ((k & 3) == 1) a1 += v;
            else if ((k & 3) == 2) a2 += v;
            else                   a3 += v;
        }
        partial[s * TILE_R + r] = (a0 + a1) + (a2 + a3);

        // ---- pack + stage next tile into the other LDS buffer ----
        if (t + 1 < TPB) {
            #pragma unroll
            for (int j = 0; j < 16; ++j) {
                int i = tid + BLK * j;
                unsigned m = (unsigned)(A[j].x & 1) | ((unsigned)(A[j].y & 1) << 8)
                           | ((unsigned)(A[j].z & 1) << 16) | ((unsigned)(A[j].w & 1) << 24);
                xb[cur ^ 1][(i >> 7) * XSTR + (i & 127)] = m;
            }
        }
        __syncthreads();   // partial ready AND next buffer staged

        if (s == 0) {
            float o = logE[gtot];
            #pragma unroll
            for (int q = 0; q < 8; ++q) o += partial[q * TILE_R + r];
            out[row0 + t * TILE_R + r] = o;
        }
    }
}

extern "C" void kernel_launch(void* const* d_in, const int* in_sizes, int n_in,
                              void* d_out, int out_size, void* d_ws, size_t ws_size,
                              hipStream_t stream)
{
    const int*   x    = (const int*)d_in[0];
    const float* W    = (const float*)d_in[1];
    const float* endW = (const float*)d_in[2];
    float*       out  = (float*)d_out;

    unsigned* T16  = (unsigned*)d_ws;                               // 512*528*4 = 1,081,344 B
    float*    logE = (float*)((char*)d_ws + (size_t)TROWS * T16STR * sizeof(unsigned));

    {
        int total  = TROWS * TCOLS;
        int blocks = (total + BLK - 1) / BLK;
        build_table_kernel<<<blocks, BLK, 0, stream>>>(W, endW, T16, logE);
    }
    pc_main_kernel<<<BB / (TILE_R * TPB), BLK, 0, stream>>>(x, T16, logE, out);
}

// Round 15
// 194.536 us; speedup vs baseline: 1.0567x; 1.0567x over previous
//
#include <hip/hip_runtime.h>
#include <math.h>

#define NN      512     // N (columns of x)
#define KK      513     // K
#define BB      65536   // batch
#define TROWS   512     // table rows, t = 0..511
#define TCOLS   513     // table cols, g = 0..512
#define T16STR  528     // u32 stride per table row (2112 B, 64B-aligned)

#define TILE_R  32            // rows per tile
#define TPB     2             // tiles per block (software pipeline)
#define BLK     256           // 4 waves; thread = (row r=tid&31, seg s=tid>>5)
#define XSTR    129           // LDS words per row (128 chunks + 1 pad)
#define TILE_I4 (TILE_R * NN / 4)   // int4 per tile = 4096

typedef int iv4 __attribute__((ext_vector_type(4)));

__device__ __forceinline__ unsigned f2bf(float f) {   // RNE f32 -> bf16 (finite only)
    unsigned u = __float_as_uint(f);
    return (u + 0x7fffu + ((u >> 16) & 1u)) >> 16;
}

// T16[t*T16STR + g] = pack(bf16 logsm(c=0), bf16 logsm(c=1)); edges/unreachable = 0.
// Block 0 wave 0 additionally builds logE[k] = endW[k] - lse(endW).
__global__ void build_table_kernel(const float* __restrict__ W, const float* __restrict__ endW,
                                   unsigned* __restrict__ T16, float* __restrict__ logE) {
    int idx = blockIdx.x * blockDim.x + threadIdx.x;
    if (idx < TROWS * TCOLS) {
        int t = idx / TCOLS;
        int g = idx - t * TCOLS;
        float v0 = 0.f, v1 = 0.f;
        if (t >= 1 && g >= 1 && g <= t) {
            const float* w = W + ((size_t)(t - 1) * (KK - 1) + (g - 1)) * 2;
            float w0 = w[0], w1 = w[1];
            float m  = fmaxf(w0, w1);
            float lse = m + __logf(__expf(w0 - m) + __expf(w1 - m));
            v0 = w0 - lse;
            v1 = w1 - lse;
        }
        T16[t * T16STR + g] = f2bf(v0) | (f2bf(v1) << 16);
    }
    if (blockIdx.x == 0 && threadIdx.x < 64) {
        int lane = threadIdx.x;
        float vals[9];
        float m = -1e30f;
        #pragma unroll
        for (int k = 0; k < 9; ++k) {
            int i = lane + 64 * k;
            vals[k] = (i < KK) ? endW[i] : -1e30f;
            m = fmaxf(m, vals[k]);
        }
        #pragma unroll
        for (int d = 32; d >= 1; d >>= 1) m = fmaxf(m, __shfl_xor(m, d, 64));
        float s = 0.f;
        #pragma unroll
        for (int k = 0; k < 9; ++k) s += __expf(vals[k] - m);
        #pragma unroll
        for (int d = 32; d >= 1; d >>= 1) s += __shfl_xor(s, d, 64);
        float lse = m + __logf(s);
        #pragma unroll
        for (int k = 0; k < 9; ++k) {
            int i = lane + 64 * k;
            if (i < KK) logE[i] = endW[i] - lse;
        }
    }
}

// 256 threads = 32 rows x 8 segs(64 cols); 2-tile software pipeline.
// Per tile: read own-seg words (LDS, conflict-free), popc+prefix -> g, issue
// ALL 64 gathers, consume 48, issue next tile's 16 staged loads (younger than
// every gather -> no consume drains them), consume last 16, pack+ds_write
// staged, barrier, reduce. Staged loads stream on HBM during the gather
// phase -> load/gather phases overlap device-wide. 1024 blocks = 4 blocks/CU:
// cross-block TLP staggers the phases and absorbs load-balance jitter
// (TPB=4 at 2 blocks/CU measured WORSE: 205 vs 194).
__global__ __launch_bounds__(BLK, 4) void pc_main_kernel(
    const int* __restrict__ x, const unsigned* __restrict__ T16,
    const float* __restrict__ logE, float* __restrict__ out)
{
    __shared__ unsigned xb[2][TILE_R * XSTR];   // byte-packed: word = 4 cols of one row
    __shared__ int      segsum[8 * TILE_R];
    __shared__ float    partial[8 * TILE_R];

    const int tid  = threadIdx.x;
    const int r    = tid & 31;          // row within tile
    const int s    = tid >> 5;          // 64-col segment (0..7)
    const int row0 = blockIdx.x * (TILE_R * TPB);

    const iv4* tb = (const iv4*)(x + (size_t)row0 * NN);   // TILE_I4=4096 int4 per tile

    // ---- prologue: load tile 0, pack, stage to LDS buf 0 ----
    iv4 A[16];
    #pragma unroll
    for (int j = 0; j < 16; ++j) A[j] = __builtin_nontemporal_load(&tb[tid + BLK * j]);
    #pragma unroll
    for (int j = 0; j < 16; ++j) {
        int i = tid + BLK * j;
        unsigned m = (unsigned)(A[j].x & 1) | ((unsigned)(A[j].y & 1) << 8)
                   | ((unsigned)(A[j].z & 1) << 16) | ((unsigned)(A[j].w & 1) << 24);
        xb[0][(i >> 7) * XSTR + (i & 127)] = m;
    }
    __syncthreads();

    #pragma unroll
    for (int t = 0; t < TPB; ++t) {
        // ---- own-segment words + popcount ----
        unsigned w[16];
        int ssum = 0;
        #pragma unroll
        for (int m = 0; m < 16; ++m) {
            w[m] = xb[t][r * XSTR + s * 16 + m];    // (r*129+16s+m)%32 spans banks: free
            ssum += __popc(w[m]);                   // bytes are 0x00/0x01
        }
        segsum[s * TILE_R + r] = ssum;
        __syncthreads();

        int g = 0, gtot = 0;
        #pragma unroll
        for (int q = 0; q < 8; ++q) {
            int v = segsum[q * TILE_R + r];
            if (q < s) g += v;
            gtot += v;
        }

        // ---- issue ALL 64 gathers (one table row pair per wave-instr) ----
        unsigned u[64];
        const unsigned* Ts = T16 + (size_t)(s * 64) * T16STR;
        #pragma unroll
        for (int m = 0; m < 16; ++m) {
            #pragma unroll
            for (int q = 0; q < 4; ++q) {
                int b = (w[m] >> (8 * q)) & 1;
                g += b;
                u[4 * m + q] = Ts[(4 * m + q) * T16STR + g];
            }
        }

        // ---- consume gathers 0..47 ----
        float a0 = 0.f, a1 = 0.f, a2 = 0.f, a3 = 0.f;
        #pragma unroll
        for (int k = 0; k < 48; ++k) {
            int b = (w[k >> 2] >> (8 * (k & 3))) & 1;
            float v = __uint_as_float(b ? (u[k] & 0xffff0000u) : (u[k] << 16));
            if      ((k & 3) == 0) a0 += v;
            else if ((k & 3) == 1) a1 += v;
            else if ((k & 3) == 2) a2 += v;
            else                   a3 += v;
        }

        // ---- issue next tile's staged loads (younger than all gathers) ----
        if (t + 1 < TPB) {
            __builtin_amdgcn_sched_barrier(0);
            #pragma unroll
            for (int j = 0; j < 16; ++j)
                A[j] = __builtin_nontemporal_load(&tb[TILE_I4 + tid + BLK * j]);
            __builtin_amdgcn_sched_barrier(0);
        }

        // ---- consume gathers 48..63 (older than staged: no drain) ----
        #pragma unroll
        for (int k = 48; k < 64; ++k) {
            int b = (w[k >> 2] >> (8 * (k & 3))) & 1;
            float v = __uint_as_float(b ? (u[k] & 0xffff0000u) : (u[k] << 16));
            if      ((k & 3) == 0) a0 += v;
            else if ((k & 3) == 1) a1 += v;
            else if ((k & 3) == 2) a2 += v;
            else                   a3 += v;
        }
        partial[s * TILE_R + r] = (a0 + a1) + (a2 + a3);

        // ---- pack + stage next tile into the other LDS buffer ----
        if (t + 1 < TPB) {
            #pragma unroll
            for (int j = 0; j < 16; ++j) {
                int i = tid + BLK * j;
                unsigned m = (unsigned)(A[j].x & 1) | ((unsigned)(A[j].y & 1) << 8)
                           | ((unsigned)(A[j].z & 1) << 16) | ((unsigned)(A[j].w & 1) << 24);
                xb[t + 1][(i >> 7) * XSTR + (i & 127)] = m;
            }
        }
        __syncthreads();   // partial ready AND next buffer staged

        if (s == 0) {
            float o = logE[gtot];
            #pragma unroll
            for (int q = 0; q < 8; ++q) o += partial[q * TILE_R + r];
            out[row0 + t * TILE_R + r] = o;
        }
    }
}

extern "C" void kernel_launch(void* const* d_in, const int* in_sizes, int n_in,
                              void* d_out, int out_size, void* d_ws, size_t ws_size,
                              hipStream_t stream)
{
    const int*   x    = (const int*)d_in[0];
    const float* W    = (const float*)d_in[1];
    const float* endW = (const float*)d_in[2];
    float*       out  = (float*)d_out;

    unsigned* T16  = (unsigned*)d_ws;                               // 512*528*4 = 1,081,344 B
    float*    logE = (float*)((char*)d_ws + (size_t)TROWS * T16STR * sizeof(unsigned));

    {
        int total  = TROWS * TCOLS;
        int blocks = (total + BLK - 1) / BLK;
        build_table_kernel<<<blocks, BLK, 0, stream>>>(W, endW, T16, logE);
    }
    pc_main_kernel<<<BB / (TILE_R * TPB), BLK, 0, stream>>>(x, T16, logE, out);
}